// Round 6
// baseline (299.610 us; speedup 1.0000x reference)
//
#include <hip/hip_runtime.h>
#include <hip/hip_fp16.h>

#define HID 64
#define ELLK 32   // slots/node; kept degree ~Poisson(5.5), max over 100k ~18
#define CUT_D2 132.5471f   // drop rbf < 1e-5 (R10: measured no absmax change)

typedef _Float16 half8 __attribute__((ext_vector_type(8)));
typedef float f32x4 __attribute__((ext_vector_type(4)));

__device__ __forceinline__ float rbf_of(unsigned w) {
    return __half2float(__ushort_as_half((unsigned short)(w & 0x7fff)));
}

// x16[n][h] = fp16(emb[z[n]][h]); also zeroes ELL counters (rides this kernel).
__global__ void embed_kernel(const int* __restrict__ z, const float* __restrict__ emb,
                             __half* __restrict__ x16, int* __restrict__ cnt, int n) {
    int t = blockIdx.x * blockDim.x + threadIdx.x;
    if (t <= n) cnt[t] = 0;
    if (t >= n * HID / 2) return;
    int node = t >> 5, h2 = (t & 31) * 2;
    const float* src = emb + z[node] * HID + h2;
    __half2 v;
    v.x = __float2half(src[0]);
    v.y = __float2half(src[1]);
    *(__half2*)(x16 + (size_t)node * HID + h2) = v;
}

// ELL fill + fused rbf for KEPT edges; packed record (col<<15)|fp16(rbf).
__global__ void fill_kernel(const int* __restrict__ row, const int* __restrict__ col,
                            const float* __restrict__ pos, int* __restrict__ cnt,
                            unsigned* __restrict__ ell, int e) {
    int t = blockIdx.x * blockDim.x + threadIdx.x;
    if (t >= e) return;
    int r = row[t], c = col[t];
    float dx = pos[3 * r]     - pos[3 * c];
    float dy = pos[3 * r + 1] - pos[3 * c + 1];
    float dz = pos[3 * r + 2] - pos[3 * c + 2];
    float d2 = dx * dx + dy * dy + dz * dz;
    if (d2 > CUT_D2) return;
    float rbf = expf(-sqrtf(d2));
    unsigned short hb = __half_as_ushort(__float2half(rbf));
    int p = atomicAdd(&cnt[r], 1);
    if (p < ELLK) ell[(size_t)r * ELLK + p] = ((unsigned)c << 15) | (unsigned)hb;
}

// R23: fused gather+linear — WIDE-LANE GATHER (8 lanes/node x 16B).
// R22 landed the 64-VGPR-fit structure (W in block LDS, no spills). Remaining
// cost: ~105 tiny (4B/lane) load instrs + ~88 bpermutes per tile. R23 remaps
// gather lanes: 64 lanes = 8 groups x 8 lanes; group owns a node, lane owns 8 h
// (half8, 16B). One load instr now fetches 8 neighbor rows (1KB, was 2 rows);
// one shfl (per-lane src (lane&56)+i) broadcasts 8 nodes' records at once.
// Per tile: loads ~105 -> ~45, shfls ~88 -> ~32, bytes/VALU/regs unchanged.
// Slot order per (node,h), pre-mask no-op semantics, rounding points, swizzled
// tile layout, MFMA phase: ALL unchanged -> bit-identical (absmax 0.00390625).
// Runtime-reg-index hazard (rule #20): r-blocks fully unrolled, compile-time
// rec[P][r]; each block guarded by a single wave-uniform `if (8r < mcT)`.
__global__ void layer_kernel(const __half* __restrict__ x16, const int* __restrict__ cnt,
                             const unsigned* __restrict__ ell,
                             const float* __restrict__ W, const float* __restrict__ b,
                             float* __restrict__ out32, __half* __restrict__ out16, int n) {
    __shared__ __align__(16) __half ltile[4][16 * HID];   // 2KB per wave, private
    __shared__ __align__(16) __half wlds[8][64][8];       // 8KB: [frag][lane][8 halves]
    int tid = threadIdx.x;
    int lane = tid & 63;
    char* tile = (char*)&ltile[tid >> 6][0];

    int grp = lane >> 3;               // gather: group = node within pass (0..7)
    int gl  = lane & 7;                // gather: lane within group = h-chunk (8 h each)
    int r16 = lane & 15;               // mfma: A row / out col
    int quad = lane >> 4;              // mfma: k-chunk / out row group

    // ---- W -> LDS preload (block-cooperative, 512 frag-slots, 2/thread) ----
#pragma unroll
    for (int s0 = 0; s0 < 2; ++s0) {
        int s = tid + s0 * 256;                    // s = f*64 + l
        int f = s >> 6, l = s & 63;
        int ht = f >> 1, kt = f & 1, q = l >> 4, r = l & 15;
        const float* src = W + (ht * 16 + r) * HID + kt * 32 + q * 8;
        half8 h;
#pragma unroll
        for (int j = 0; j < 8; ++j) h[j] = (_Float16)src[j];
        *(half8*)&wlds[f][l][0] = h;
    }
    float biasv[4];
#pragma unroll
    for (int ht = 0; ht < 4; ++ht) biasv[ht] = b[ht * 16 + r16];
    __syncthreads();                               // before early-out: all waves arrive

    int wid = (blockIdx.x * blockDim.x + tid) >> 6;
    int nw = (gridDim.x * blockDim.x) >> 6;
    int ntiles = (n + 15) >> 4;
    if (wid >= ntiles) return;                     // no barriers below -> safe

    const half8* wl = (const half8*)&wlds[0][0][0];

    for (int t = wid; t < ntiles; t += nw) {
        int tbase = t << 4;

        // ---- stage A: counts + rec rows + residual rows, all in flight ----
        int crow = tbase + r16;                       // counts replicated across quads
        int myc = cnt[crow < n ? crow : n - 1];
        if (crow >= n) myc = 0;
        if (myc > ELLK) myc = ELLK;

        // my node for pass P: tbase + P*8 + grp (clamped for loads)
        int nd0 = tbase + grp;        if (nd0 >= n) nd0 = n - 1;
        int nd1 = tbase + 8 + grp;    if (nd1 >= n) nd1 = n - 1;

        // rec[P][r]: lane holds slot r*8+gl of its pass-P node (coalesced 256B/load)
        unsigned rec[2][4];
#pragma unroll
        for (int r = 0; r < 4; ++r) {
            rec[0][r] = ell[(size_t)nd0 * ELLK + r * 8 + gl];
            rec[1][r] = ell[(size_t)nd1 * ELLK + r * 8 + gl];
        }
        // residuals: lane loads 8 h of its node (16B)
        half8 res0 = *(const half8*)(x16 + (size_t)nd0 * HID + gl * 8);
        half8 res1 = *(const half8*)(x16 + (size_t)nd1 * HID + gl * 8);

        // ---- tile-wide max count (wave-uniform, branchless reduction) ----
        int m = myc;
        m = max(m, __shfl_xor(m, 1));
        m = max(m, __shfl_xor(m, 2));
        m = max(m, __shfl_xor(m, 4));
        m = max(m, __shfl_xor(m, 8));                 // max over each 16-lane group
        int mcT = __builtin_amdgcn_readfirstlane(m);

        // ---- pre-mask: dead slot -> (own row, rbf=0); exact no-op on hot line ----
        int c0 = __shfl(myc, grp);                    // count of pass-0 node
        int c1 = __shfl(myc, 8 + grp);                // count of pass-1 node
#pragma unroll
        for (int r = 0; r < 4; ++r) {
            int slot = r * 8 + gl;
            if (slot >= c0) rec[0][r] = (unsigned)nd0 << 15;   // rbf bits = 0
            if (slot >= c1) rec[1][r] = (unsigned)nd1 << 15;
        }

        float acc0[8], acc1[8];
#pragma unroll
        for (int k = 0; k < 8; ++k) {
            acc0[k] = (float)res0[k];
            acc1[k] = (float)res1[k];
        }

        // ---- gather: r-blocks of 8 slots, 16 wide loads (1KB each) per block ----
#pragma unroll
        for (int r = 0; r < 4; ++r) {
            if (8 * r < mcT) {                        // wave-uniform coarse guard
#pragma unroll
                for (int i = 0; i < 8; ++i) {
                    // one shfl serves all 8 groups: src lane = group base + i
                    unsigned w0 = __shfl(rec[0][r], (lane & 56) + i);
                    unsigned w1 = __shfl(rec[1][r], (lane & 56) + i);
                    half8 v0 = *(const half8*)(x16 + (size_t)(w0 >> 15) * HID + gl * 8);
                    half8 v1 = *(const half8*)(x16 + (size_t)(w1 >> 15) * HID + gl * 8);
                    float f0 = rbf_of(w0);            // pre-masked: 0 if dead slot
                    float f1 = rbf_of(w1);
#pragma unroll
                    for (int k = 0; k < 8; ++k) {
                        acc0[k] = fmaf((float)v0[k], f0, acc0[k]);
                        acc1[k] = fmaf((float)v1[k], f1, acc1[k]);
                    }
                }
            }
        }

        // ---- y -> swizzled LDS tile (identical layout; 16B stores) ----
        {
            half8 o0, o1;
#pragma unroll
            for (int k = 0; k < 8; ++k) {
                o0[k] = (_Float16)acc0[k];
                o1[k] = (_Float16)acc1[k];
            }
            int ni0 = grp;                            // pass-0 row in tile
            int ni1 = 8 + grp;                        // pass-1 row in tile
            *(half8*)(tile + ni0 * 128 + ((gl << 4) ^ ((ni0 & 7) << 4))) = o0;
            *(half8*)(tile + ni1 * 128 + ((gl << 4) ^ ((ni1 & 7) << 4))) = o1;
        }

        // ---- phase 2: MFMA; A-frags from wave tile, B-frags from block W-LDS ----
        half8 afrag0 = *(const half8*)(tile + r16 * 128 + ((quad << 4) ^ ((r16 & 7) << 4)));
        half8 afrag1 = *(const half8*)(tile + r16 * 128 + (((quad + 4) << 4) ^ ((r16 & 7) << 4)));
#pragma unroll
        for (int ht = 0; ht < 4; ++ht) {
            f32x4 acc = {biasv[ht], biasv[ht], biasv[ht], biasv[ht]};
            half8 b0 = wl[(ht * 2 + 0) * 64 + lane];  // stride-1 ds_read_b128
            half8 b1 = wl[(ht * 2 + 1) * 64 + lane];
            acc = __builtin_amdgcn_mfma_f32_16x16x32_f16(afrag0, b0, acc, 0, 0, 0);
            acc = __builtin_amdgcn_mfma_f32_16x16x32_f16(afrag1, b1, acc, 0, 0, 0);
#pragma unroll
            for (int r = 0; r < 4; ++r) {
                int row = tbase + quad * 4 + r;
                if (row < n) {                        // guards garbage tail rows too
                    float v = fmaxf(acc[r], 0.0f);
                    size_t idx = (size_t)row * HID + ht * 16 + r16;
                    if (out32) out32[idx] = v;
                    if (out16) out16[idx] = __float2half(v);
                }
            }
        }
    }
}

extern "C" void kernel_launch(void* const* d_in, const int* in_sizes, int n_in,
                              void* d_out, int out_size, void* d_ws, size_t ws_size,
                              hipStream_t stream) {
    const int*   z    = (const int*)d_in[0];
    const float* pos  = (const float*)d_in[1];
    const int*   eidx = (const int*)d_in[2];
    const float* emb  = (const float*)d_in[3];
    const float* Ws   = (const float*)d_in[4];
    const float* bs   = (const float*)d_in[5];
    int n = in_sizes[0];
    int e = in_sizes[2] / 2;
    int nlayers = in_sizes[4] / (HID * HID);
    const int* row = eidx;
    const int* col = eidx + e;
    float* out = (float*)d_out;

    char* ws = (char*)d_ws;
    __half*   X16 = (__half*)ws;                                   // n*64 fp16 (12.8 MB)
    __half*   Y16 = X16 + (size_t)n * HID;                         // n*64 fp16 (ping-pong)
    unsigned* ell = (unsigned*)((char*)Y16 + (size_t)n * HID * 2); // (n+2)*ELLK u32
    int*      cnt = (int*)((char*)ell + (size_t)(n + 2) * ELLK * 4); // n+1 ints

    // 5 dispatches: embed(+cnt zero), fill, 3x fused layer
    // (R16 lesson: hipLaunchCooperativeKernel does NOT survive this harness's
    // graph capture — remaining ~4 dispatch gaps are structural.)
    embed_kernel<<<(n * HID / 2 + 255) / 256, 256, 0, stream>>>(z, emb, X16, cnt, n);
    fill_kernel<<<(e + 255) / 256, 256, 0, stream>>>(row, col, pos, cnt, ell, e);

    int ntiles = (n + 15) >> 4;
    int lblocks = (ntiles + 3) >> 2;   // 4 waves/block, exactly 1 tile/wave
    for (int l = 0; l < nlayers; ++l) {
        bool last = (l == nlayers - 1);
        const __half* src = (l & 1) ? Y16 : X16;   // ping-pong: fused kernel reads
        __half*       dst = (l & 1) ? X16 : Y16;   // src everywhere while writing dst
        layer_kernel<<<lblocks, 256, 0, stream>>>(src, cnt, ell,
                                                  Ws + (size_t)l * HID * HID,
                                                  bs + (size_t)l * HID,
                                                  last ? out : nullptr,
                                                  last ? nullptr : dst, n);
    }
}

// Round 7
// 210.843 us; speedup vs baseline: 1.4210x; 1.4210x over previous
//
#include <hip/hip_runtime.h>
#include <hip/hip_fp16.h>

#define HID 64
#define ELLK 32   // slots/node; kept degree ~Poisson(5.5), max over 100k ~18
#define CUT_D2 132.5471f   // drop rbf < 1e-5 (R10: measured no absmax change)

typedef _Float16 half8 __attribute__((ext_vector_type(8)));
typedef float f32x4 __attribute__((ext_vector_type(4)));

__device__ __forceinline__ float rbf_of(unsigned w) {
    return __half2float(__ushort_as_half((unsigned short)(w & 0x7fff)));
}

// x16[n][h] = fp16(emb[z[n]][h]); also zeroes ELL counters (rides this kernel).
__global__ void embed_kernel(const int* __restrict__ z, const float* __restrict__ emb,
                             __half* __restrict__ x16, int* __restrict__ cnt, int n) {
    int t = blockIdx.x * blockDim.x + threadIdx.x;
    if (t <= n) cnt[t] = 0;
    if (t >= n * HID / 2) return;
    int node = t >> 5, h2 = (t & 31) * 2;
    const float* src = emb + z[node] * HID + h2;
    __half2 v;
    v.x = __float2half(src[0]);
    v.y = __float2half(src[1]);
    *(__half2*)(x16 + (size_t)node * HID + h2) = v;
}

// ELL fill + fused rbf for KEPT edges; packed record (col<<15)|fp16(rbf).
__global__ void fill_kernel(const int* __restrict__ row, const int* __restrict__ col,
                            const float* __restrict__ pos, int* __restrict__ cnt,
                            unsigned* __restrict__ ell, int e) {
    int t = blockIdx.x * blockDim.x + threadIdx.x;
    if (t >= e) return;
    int r = row[t], c = col[t];
    float dx = pos[3 * r]     - pos[3 * c];
    float dy = pos[3 * r + 1] - pos[3 * c + 1];
    float dz = pos[3 * r + 2] - pos[3 * c + 2];
    float d2 = dx * dx + dy * dy + dz * dz;
    if (d2 > CUT_D2) return;
    float rbf = expf(-sqrtf(d2));
    unsigned short hb = __half_as_ushort(__float2half(rbf));
    int p = atomicAdd(&cnt[r], 1);
    if (p < ELLK) ell[(size_t)r * ELLK + p] = ((unsigned)c << 15) | (unsigned)hb;
}

// R24: SPLIT structure (round-0 champion, 213us) + WIDE-LANE gather.
// Fusion verdict after 6 rounds (232/329/336/272/225/300 vs 213): the fused
// wave must hold gather-MLP state AND MFMA state in the 64 VGPRs the backend
// insists on -> spills every time the in-flight window is sized for latency.
// Split gather owns the full 64-reg budget for MLP. Wide-lane remap (R23's
// idea, register-feasible here): 64 lanes = 8 groups x 8 lanes; group = node,
// lane = half8 h-chunk (16B). One load instr = 8 neighbor rows (1KB, was 2);
// one shfl broadcasts 8 nodes' records. In-flight = 8 half8 loads = 32 VGPR
// dest + ~20 state -> fits 64 by construction (R23 needed 64 dest alone).
// Slot order per (node,h) ascending, residual-first init, same fma chain,
// pre-mask -> (own row, rbf=0) exact no-ops: bit-identical (absmax 0.00390625).
__global__ void gather_kernel(const __half* __restrict__ x16, const int* __restrict__ cnt,
                              const unsigned* __restrict__ ell,
                              __half* __restrict__ y16, int n) {
    int lane = threadIdx.x & 63;
    int grp = lane >> 3;               // group = node within the wave's 8-node pack
    int gl  = lane & 7;                // lane within group = h-chunk (8 h each)
    int wid = (blockIdx.x * blockDim.x + threadIdx.x) >> 6;
    int nw = (gridDim.x * blockDim.x) >> 6;
    int npack = (n + 7) >> 3;          // packs of 8 nodes (n=100k: exact, no tail)
    for (int p = wid; p < npack; p += nw) {
        int n8 = p << 3;
        int own = n8 + grp; if (own >= n) own = n - 1;     // clamp (loads only)

        // counts: lane holds cnt of node n8+(lane&7); group g's count = shfl(.,g)
        int cn = n8 + (lane & 7);
        int myc = cnt[cn < n ? cn : n - 1];
        if (cn >= n) myc = 0;
        if (myc > ELLK) myc = ELLK;

        // rec[r]: slot r*8+gl of own node (coalesced 128B/group, 1KB/wave/r)
        unsigned rec[4];
#pragma unroll
        for (int r = 0; r < 4; ++r)
            rec[r] = ell[(size_t)own * ELLK + r * 8 + gl];

        // residual: 8 h of own node (16B)
        half8 res = *(const half8*)(x16 + (size_t)own * HID + gl * 8);

        // pack-wide max count (lanes 0-7 hold all 8 counts; pattern repeats /8)
        int m = myc;
        m = max(m, __shfl_xor(m, 1));
        m = max(m, __shfl_xor(m, 2));
        m = max(m, __shfl_xor(m, 4));
        int mcT = __builtin_amdgcn_readfirstlane(m);

        // pre-mask: dead slot -> (own row, rbf=0); exact no-op on hot line
        int c_own = __shfl(myc, grp);
#pragma unroll
        for (int r = 0; r < 4; ++r)
            if (r * 8 + gl >= c_own) rec[r] = (unsigned)own << 15;

        float acc[8];
#pragma unroll
        for (int k = 0; k < 8; ++k) acc[k] = (float)res[k];

        // gather: r-blocks of 8 slots; 8 wide loads (1KB each) in flight/block
#pragma unroll
        for (int r = 0; r < 4; ++r) {
            if (8 * r < mcT) {                         // wave-uniform coarse guard
#pragma unroll
                for (int i = 0; i < 8; ++i) {
                    // one shfl serves all 8 groups: src lane = grp*8 + i
                    unsigned w = __shfl(rec[r], (lane & 56) + i);
                    half8 v = *(const half8*)(x16 + (size_t)(w >> 15) * HID + gl * 8);
                    float f = rbf_of(w);               // pre-masked: 0 if dead
#pragma unroll
                    for (int k = 0; k < 8; ++k)
                        acc[k] = fmaf((float)v[k], f, acc[k]);
                }
            }
        }

        half8 o;
#pragma unroll
        for (int k = 0; k < 8; ++k) o[k] = (_Float16)acc[k];
        if (n8 + grp < n)
            *(half8*)(y16 + (size_t)(n8 + grp) * HID + gl * 8) = o;
    }
}

// MFMA linear (layouts HW-verified): out = relu(Y·Wᵀ + b), 16-node×64-h
// tile/wave, mfma_f32_16x16x32_f16. A-frags load directly from fp16 y16;
// writes fp16 x16 for the next layer; fp32 d_out only on the final layer.
// (round-0 version, byte-identical)
__global__ void linear_kernel(const __half* __restrict__ y16, const float* __restrict__ W,
                              const float* __restrict__ b, float* __restrict__ out32,
                              __half* __restrict__ out16, int n) {
    int lane = threadIdx.x & 63;
    int r16 = lane & 15;
    int quad = lane >> 4;
    int wid = (blockIdx.x * blockDim.x + threadIdx.x) >> 6;
    int nw = (gridDim.x * blockDim.x) >> 6;

    half8 bfrag[4][2];
    float biasv[4];
#pragma unroll
    for (int ht = 0; ht < 4; ++ht) {
#pragma unroll
        for (int kt = 0; kt < 2; ++kt) {
            const float* src = W + (ht * 16 + r16) * HID + kt * 32 + quad * 8;
            half8 h;
#pragma unroll
            for (int j = 0; j < 8; ++j) h[j] = (_Float16)src[j];
            bfrag[ht][kt] = h;
        }
        biasv[ht] = b[ht * 16 + r16];
    }

    int ntiles = (n + 15) >> 4;
    for (int t = wid; t < ntiles; t += nw) {
        int base = t << 4;
        int arow = base + r16;
        if (arow >= n) arow = n - 1;              // tail clamp (loads only)
        const __half* yr = y16 + (size_t)arow * HID + quad * 8;
        half8 afrag0 = *(const half8*)(yr);
        half8 afrag1 = *(const half8*)(yr + 32);
#pragma unroll
        for (int ht = 0; ht < 4; ++ht) {
            f32x4 acc = {biasv[ht], biasv[ht], biasv[ht], biasv[ht]};
            acc = __builtin_amdgcn_mfma_f32_16x16x32_f16(afrag0, bfrag[ht][0], acc, 0, 0, 0);
            acc = __builtin_amdgcn_mfma_f32_16x16x32_f16(afrag1, bfrag[ht][1], acc, 0, 0, 0);
#pragma unroll
            for (int r = 0; r < 4; ++r) {
                int row = base + quad * 4 + r;
                if (row < n) {
                    float v = fmaxf(acc[r], 0.0f);
                    size_t idx = (size_t)row * HID + ht * 16 + r16;
                    if (out32) out32[idx] = v;
                    if (out16) out16[idx] = __float2half(v);
                }
            }
        }
    }
}

extern "C" void kernel_launch(void* const* d_in, const int* in_sizes, int n_in,
                              void* d_out, int out_size, void* d_ws, size_t ws_size,
                              hipStream_t stream) {
    const int*   z    = (const int*)d_in[0];
    const float* pos  = (const float*)d_in[1];
    const int*   eidx = (const int*)d_in[2];
    const float* emb  = (const float*)d_in[3];
    const float* Ws   = (const float*)d_in[4];
    const float* bs   = (const float*)d_in[5];
    int n = in_sizes[0];
    int e = in_sizes[2] / 2;
    int nlayers = in_sizes[4] / (HID * HID);
    const int* row = eidx;
    const int* col = eidx + e;
    float* out = (float*)d_out;

    char* ws = (char*)d_ws;
    __half*   X16 = (__half*)ws;                                   // n*64 fp16 (12.8 MB)
    __half*   Y16 = X16 + (size_t)n * HID;                         // n*64 fp16 (12.8 MB)
    unsigned* ell = (unsigned*)((char*)Y16 + (size_t)n * HID * 2); // (n+2)*ELLK u32
    int*      cnt = (int*)((char*)ell + (size_t)(n + 2) * ELLK * 4); // n+1 ints

    // 8 dispatches: embed(+cnt zero), fill, 3x(gather, linear)
    // (R16 lesson: hipLaunchCooperativeKernel does NOT survive this harness's
    // graph capture — the ~50us of dispatch gaps are structural.)
    embed_kernel<<<(n * HID / 2 + 255) / 256, 256, 0, stream>>>(z, emb, X16, cnt, n);
    fill_kernel<<<(e + 255) / 256, 256, 0, stream>>>(row, col, pos, cnt, ell, e);

    int npack = (n + 7) >> 3;                       // 8 nodes per wave
    int gblocks = (npack + 3) >> 2;                 // 4 waves/block -> 1 pack/wave
    for (int l = 0; l < nlayers; ++l) {
        bool last = (l == nlayers - 1);
        gather_kernel<<<gblocks, 256, 0, stream>>>(X16, cnt, ell, Y16, n);
        linear_kernel<<<1024, 256, 0, stream>>>(Y16, Ws + (size_t)l * HID * HID,
                                                bs + (size_t)l * HID,
                                                last ? out : nullptr,
                                                last ? nullptr : X16, n);
    }
}

// Round 8
// 176.211 us; speedup vs baseline: 1.7003x; 1.1965x over previous
//
#include <hip/hip_runtime.h>
#include <hip/hip_fp16.h>

#define HID 64
#define ELLK 32   // slots/node; kept degree ~Poisson(5.5), max over 100k ~18
#define CUT_D2 132.5471f   // drop rbf < 1e-5 (R10: measured no absmax change)

typedef _Float16 half8 __attribute__((ext_vector_type(8)));
typedef float f32x4 __attribute__((ext_vector_type(4)));

__device__ __forceinline__ float rbf_of(unsigned w) {
    return __half2float(__ushort_as_half((unsigned short)(w & 0x7fff)));
}

// x16[n][h] = fp16(emb[z[n]][h]); also zeroes ELL counters (rides this kernel).
__global__ void embed_kernel(const int* __restrict__ z, const float* __restrict__ emb,
                             __half* __restrict__ x16, int* __restrict__ cnt, int n) {
    int t = blockIdx.x * blockDim.x + threadIdx.x;
    if (t <= n) cnt[t] = 0;
    if (t >= n * HID / 2) return;
    int node = t >> 5, h2 = (t & 31) * 2;
    const float* src = emb + z[node] * HID + h2;
    __half2 v;
    v.x = __float2half(src[0]);
    v.y = __float2half(src[1]);
    *(__half2*)(x16 + (size_t)node * HID + h2) = v;
}

// ELL fill + fused rbf for KEPT edges; packed record (col<<15)|fp16(rbf).
__global__ void fill_kernel(const int* __restrict__ row, const int* __restrict__ col,
                            const float* __restrict__ pos, int* __restrict__ cnt,
                            unsigned* __restrict__ ell, int e) {
    int t = blockIdx.x * blockDim.x + threadIdx.x;
    if (t >= e) return;
    int r = row[t], c = col[t];
    float dx = pos[3 * r]     - pos[3 * c];
    float dy = pos[3 * r + 1] - pos[3 * c + 1];
    float dz = pos[3 * r + 2] - pos[3 * c + 2];
    float d2 = dx * dx + dy * dy + dz * dz;
    if (d2 > CUT_D2) return;
    float rbf = expf(-sqrtf(d2));
    unsigned short hb = __half_as_ushort(__float2half(rbf));
    int p = atomicAdd(&cnt[r], 1);
    if (p < ELLK) ell[(size_t)r * ELLK + p] = ((unsigned)c << 15) | (unsigned)hb;
}

// R25: fused layer via WAVE SPECIALIZATION (not wave serialization).
// Budget solve across R18-R24: gather~20us, linear~8us, but dispatch gap ~15us
// -> ~105us of the 210 total is gaps. Fusion kept losing because ONE wave held
// gather-MLP state AND MFMA state inside the allocator's hard 64-VGPR target.
// R25: 512-thread block = 8 waves, block owns 4 MFMA tiles (64 nodes).
//   gather phase: each wave = ONE 8-node pack, R24 wide-lane gather VERBATIM
//     (same per-wave chain & parallelism as the split champion: 12.5k waves),
//     y -> swizzled LDS tile. Gather-state-only registers (~55, R24-proven).
//   __syncthreads (single barrier, all 512 threads).
//   mfma phase: wave w -> tile (w&3), ht-half (w>>2); W from block LDS (R22),
//     2 waves per tile. MFMA-state-only registers (~30).
// Never both states at once -> fits 64 VGPRs by construction.
// Dispatches 8 -> 5. Math/slot order/rounding identical -> absmax 0.00390625.
__global__ void __launch_bounds__(512)
layer_kernel(const __half* __restrict__ x16, const int* __restrict__ cnt,
             const unsigned* __restrict__ ell,
             const float* __restrict__ W, const float* __restrict__ b,
             float* __restrict__ out32, __half* __restrict__ out16, int n) {
    __shared__ __align__(16) __half ltile[4][16 * HID];   // 8KB: 4 tiles
    __shared__ __align__(16) __half wlds[8][64][8];       // 8KB: [frag][lane][8 halves]
    int tid = threadIdx.x;
    int lane = tid & 63;
    int wv = tid >> 6;                 // wave 0..7

    int grp = lane >> 3;               // gather: group = node within the pack
    int gl  = lane & 7;                // gather: lane within group = h-chunk
    int r16 = lane & 15;               // mfma: A row / out col
    int quad = lane >> 4;              // mfma: k-chunk / out row group

    // ---- W -> LDS preload (512 threads, 512 frag-slots, 1 each) ----
    {
        int f = tid >> 6, l = tid & 63;
        int ht = f >> 1, kt = f & 1, q = l >> 4, r = l & 15;
        const float* src = W + (ht * 16 + r) * HID + kt * 32 + q * 8;
        half8 h;
#pragma unroll
        for (int j = 0; j < 8; ++j) h[j] = (_Float16)src[j];
        *(half8*)&wlds[f][l][0] = h;
    }
    float biasv[4];
#pragma unroll
    for (int ht = 0; ht < 4; ++ht) biasv[ht] = b[ht * 16 + r16];
    __syncthreads();

    int ntiles = (n + 15) >> 4;
    int Tb = blockIdx.x << 2;          // first tile of this block

    // ================= gather phase: one 8-node pack per wave =================
    {
        int n8 = (Tb << 4) + (wv << 3);                    // pack base node
        int own = n8 + grp; if (own >= n) own = n - 1;     // clamp (loads only)

        int cn = n8 + (lane & 7);
        int myc = cnt[cn < n ? cn : n - 1];
        if (cn >= n) myc = 0;
        if (myc > ELLK) myc = ELLK;

        unsigned rec[4];
#pragma unroll
        for (int r = 0; r < 4; ++r)
            rec[r] = ell[(size_t)own * ELLK + r * 8 + gl];

        half8 res = *(const half8*)(x16 + (size_t)own * HID + gl * 8);

        int m = myc;
        m = max(m, __shfl_xor(m, 1));
        m = max(m, __shfl_xor(m, 2));
        m = max(m, __shfl_xor(m, 4));
        int mcT = __builtin_amdgcn_readfirstlane(m);

        int c_own = __shfl(myc, grp);
#pragma unroll
        for (int r = 0; r < 4; ++r)
            if (r * 8 + gl >= c_own) rec[r] = (unsigned)own << 15;  // rbf=0 no-op

        float acc[8];
#pragma unroll
        for (int k = 0; k < 8; ++k) acc[k] = (float)res[k];

#pragma unroll
        for (int r = 0; r < 4; ++r) {
            if (8 * r < mcT) {                         // wave-uniform coarse guard
#pragma unroll
                for (int i = 0; i < 8; ++i) {
                    unsigned w = __shfl(rec[r], (lane & 56) + i);
                    half8 v = *(const half8*)(x16 + (size_t)(w >> 15) * HID + gl * 8);
                    float f = rbf_of(w);               // pre-masked: 0 if dead
#pragma unroll
                    for (int k = 0; k < 8; ++k)
                        acc[k] = fmaf((float)v[k], f, acc[k]);
                }
            }
        }

        half8 o;
#pragma unroll
        for (int k = 0; k < 8; ++k) o[k] = (_Float16)acc[k];
        // wave wv -> tile wv/2, rows (wv&1)*8+grp; swizzled (R23 layout)
        char* tile = (char*)&ltile[wv >> 1][0];
        int ni = ((wv & 1) << 3) + grp;
        *(half8*)(tile + ni * 128 + ((gl << 4) ^ ((ni & 7) << 4))) = o;
    }
    __syncthreads();

    // ================= mfma phase: wave w -> tile (w&3), ht-half (w>>2) =======
    {
        int tw = wv & 3;
        int t = Tb + tw;
        if (t < ntiles) {
            int tbase = t << 4;
            char* tile = (char*)&ltile[tw][0];
            const half8* wl = (const half8*)&wlds[0][0][0];
            half8 afrag0 = *(const half8*)(tile + r16 * 128 + ((quad << 4) ^ ((r16 & 7) << 4)));
            half8 afrag1 = *(const half8*)(tile + r16 * 128 + (((quad + 4) << 4) ^ ((r16 & 7) << 4)));
            int htb = (wv >> 2) << 1;                  // 0 or 2
#pragma unroll
            for (int hh = 0; hh < 2; ++hh) {
                int ht = htb + hh;
                f32x4 acc = {biasv[ht], biasv[ht], biasv[ht], biasv[ht]};
                half8 b0 = wl[(ht * 2 + 0) * 64 + lane];   // stride-1 ds_read_b128
                half8 b1 = wl[(ht * 2 + 1) * 64 + lane];
                acc = __builtin_amdgcn_mfma_f32_16x16x32_f16(afrag0, b0, acc, 0, 0, 0);
                acc = __builtin_amdgcn_mfma_f32_16x16x32_f16(afrag1, b1, acc, 0, 0, 0);
#pragma unroll
                for (int r = 0; r < 4; ++r) {
                    int row = tbase + quad * 4 + r;
                    if (row < n) {                     // guards garbage tail rows too
                        float v = fmaxf(acc[r], 0.0f);
                        size_t idx = (size_t)row * HID + ht * 16 + r16;
                        if (out32) out32[idx] = v;
                        if (out16) out16[idx] = __float2half(v);
                    }
                }
            }
        }
    }
}

extern "C" void kernel_launch(void* const* d_in, const int* in_sizes, int n_in,
                              void* d_out, int out_size, void* d_ws, size_t ws_size,
                              hipStream_t stream) {
    const int*   z    = (const int*)d_in[0];
    const float* pos  = (const float*)d_in[1];
    const int*   eidx = (const int*)d_in[2];
    const float* emb  = (const float*)d_in[3];
    const float* Ws   = (const float*)d_in[4];
    const float* bs   = (const float*)d_in[5];
    int n = in_sizes[0];
    int e = in_sizes[2] / 2;
    int nlayers = in_sizes[4] / (HID * HID);
    const int* row = eidx;
    const int* col = eidx + e;
    float* out = (float*)d_out;

    char* ws = (char*)d_ws;
    __half*   X16 = (__half*)ws;                                   // n*64 fp16 (12.8 MB)
    __half*   Y16 = X16 + (size_t)n * HID;                         // n*64 fp16 (ping-pong)
    unsigned* ell = (unsigned*)((char*)Y16 + (size_t)n * HID * 2); // (n+2)*ELLK u32
    int*      cnt = (int*)((char*)ell + (size_t)(n + 2) * ELLK * 4); // n+1 ints

    // 5 dispatches: embed(+cnt zero), fill, 3x fused layer (wave-specialized)
    // (R16 lesson: hipLaunchCooperativeKernel does NOT survive this harness's
    // graph capture — remaining ~4 dispatch gaps are structural.)
    embed_kernel<<<(n * HID / 2 + 255) / 256, 256, 0, stream>>>(z, emb, X16, cnt, n);
    fill_kernel<<<(e + 255) / 256, 256, 0, stream>>>(row, col, pos, cnt, ell, e);

    int ntiles = (n + 15) >> 4;
    int lblocks = (ntiles + 3) >> 2;   // 4 tiles/block (8 waves: 8 packs)
    for (int l = 0; l < nlayers; ++l) {
        bool last = (l == nlayers - 1);
        const __half* src = (l & 1) ? Y16 : X16;   // ping-pong: fused kernel reads
        __half*       dst = (l & 1) ? X16 : Y16;   // src everywhere while writing dst
        layer_kernel<<<lblocks, 512, 0, stream>>>(src, cnt, ell,
                                                  Ws + (size_t)l * HID * HID,
                                                  bs + (size_t)l * HID,
                                                  last ? out : nullptr,
                                                  last ? nullptr : dst, n);
    }
}